// Round 19
// baseline (236.309 us; speedup 1.0000x reference)
//
#include <hip/hip_runtime.h>

typedef unsigned short u16;
typedef __attribute__((ext_vector_type(4))) float f32x4;
typedef __attribute__((ext_vector_type(8))) __bf16 bf16x8;
typedef __attribute__((ext_vector_type(4))) unsigned int u32x4;

#define S_LEN 2048
#define D_DIM 1024
#define N_HEADS 16
#define DK 64
#define B_SZ 4

__device__ __forceinline__ u16 f2bf(float f) {
  unsigned int u = __float_as_uint(f);
  unsigned int r = (u + 0x7FFFu + ((u >> 16) & 1u)) >> 16;
  return (u16)r;
}
__device__ __forceinline__ unsigned int cvtpk(float a, float b) {
  unsigned int r;
  asm("v_cvt_pk_bf16_f32 %0, %1, %2" : "=v"(r) : "v"(a), "v"(b));
  return r;  // low16 = bf16(a), high16 = bf16(b)
}
__device__ __forceinline__ f32x4 mfma16(u32x4 a, u32x4 b, f32x4 c) {
  return __builtin_amdgcn_mfma_f32_16x16x32_bf16(
      __builtin_bit_cast(bf16x8, a), __builtin_bit_cast(bf16x8, b), c, 0, 0, 0);
}
// async global->LDS, 16B/lane; LDS dest = wave-uniform base + lane*16
__device__ __forceinline__ void gload_lds16(const void* g, void* l) {
  __builtin_amdgcn_global_load_lds(
      (const __attribute__((address_space(1))) void*)g,
      (__attribute__((address_space(3))) void*)l, 16, 0, 0);
}

// ---- fused weight transposes: WT[n][k] (bf16) = W[k][n] (f32) --------------
__global__ __launch_bounds__(256) void transpose_all(
    const float* __restrict__ W0, const float* __restrict__ W1,
    const float* __restrict__ W2, const float* __restrict__ W3,
    u16* __restrict__ T0, u16* __restrict__ T1,
    u16* __restrict__ T2, u16* __restrict__ T3) {
  __shared__ float tb[32][33];
  const int z = blockIdx.z;
  const float* W = (z == 0) ? W0 : (z == 1) ? W1 : (z == 2) ? W2 : W3;
  u16* WT = (z == 0) ? T0 : (z == 1) ? T1 : (z == 2) ? T2 : T3;
  const int tx = threadIdx.x & 31;
  const int ty0 = (threadIdx.x >> 5) << 2;
  const int bn = blockIdx.x << 5;
  const int bk = blockIdx.y << 5;
#pragma unroll
  for (int i = 0; i < 4; ++i)
    tb[ty0 + i][tx] = W[(size_t)(bk + ty0 + i) * D_DIM + bn + tx];
  __syncthreads();
#pragma unroll
  for (int i = 0; i < 4; ++i)
    WT[(size_t)(bn + ty0 + i) * D_DIM + bk + tx] = f2bf(tb[tx][ty0 + i]);
}

// ---- GEMM body: 256x128 tile, BK=32, 8 waves (4x2), 512 threads ------------
// LDS layouts are round-15's proven ones (timed-best 206.5us):
//   AF32 As: [256][40] u16, reg+cvtpk staging (2-way writes, free per m136)
//   bf16 As/Bs: [rows][32] linear via gload_lds, source chunk ^= (row&3),
//               reads apply the same XOR (slot algebra verified r15).
// Bigger tile cuts staging bytes/output 25% and doubles MFMA per barrier —
// the 2-phase loop's actual critical path (m252 regime).
template <int AF32, int BPRE>
__device__ __forceinline__ void gemm_body(const void* __restrict__ Av,
                                          const void* __restrict__ Bv,
                                          const float* __restrict__ bias,
                                          void* __restrict__ dstv,
                                          const int epi, const float osc,
                                          const int m0, const int n0) {
  __shared__ __align__(16) u16 As[256 * 40];
  __shared__ __align__(16) u16 Bs[128 * 40];
  const int tid = threadIdx.x;
  const int lane = tid & 63;
  const int wid = tid >> 6;          // 0..7
  const int wr = wid >> 1, wc = wid & 1;   // 4x2 wave grid
  const int lr = lane & 15, lg = lane >> 4;

  const float* Xf = (const float*)Av;
  const u16* Xh = (const u16*)Av;
  const float* Wf = (const float*)Bv;
  const u16* WT = (const u16*)Bv;

  f32x4 acc[4][4];
#pragma unroll
  for (int i = 0; i < 4; ++i)
#pragma unroll
    for (int j = 0; j < 4; ++j) acc[i][j] = (f32x4){0.f, 0.f, 0.f, 0.f};

  const int arow = tid >> 1;           // AF32 A staging row (0..255)
  const int ahalf = (tid & 1) << 4;    // 16-elem half
  const int glr = lane >> 2;                       // 0..15
  const int glc = ((lane & 3) ^ (glr & 3)) << 3;   // pre-swizzled chunk (elems)

  for (int k0 = 0; k0 < D_DIM; k0 += 32) {
    __syncthreads();
    // ---- stage A (256 rows x 32 k) ----
    if (AF32) {
      const float* src = &Xf[(size_t)(m0 + arow) * D_DIM + k0 + ahalf];
      f32x4 a0 = *(const f32x4*)src;
      f32x4 a1 = *(const f32x4*)(src + 4);
      f32x4 a2 = *(const f32x4*)(src + 8);
      f32x4 a3 = *(const f32x4*)(src + 12);
      u32x4 p0 = (u32x4){cvtpk(a0[0], a0[1]), cvtpk(a0[2], a0[3]),
                         cvtpk(a1[0], a1[1]), cvtpk(a1[2], a1[3])};
      u32x4 p1 = (u32x4){cvtpk(a2[0], a2[1]), cvtpk(a2[2], a2[3]),
                         cvtpk(a3[0], a3[1]), cvtpk(a3[2], a3[3])};
      *(u32x4*)&As[arow * 40 + ahalf] = p0;
      *(u32x4*)&As[arow * 40 + ahalf + 8] = p1;
    } else {
#pragma unroll
      for (int j = 0; j < 2; ++j) {
        const int rbase = wid * 32 + j * 16;
        gload_lds16(&Xh[(size_t)(m0 + rbase + glr) * D_DIM + k0 + glc],
                    &As[rbase * 32]);
      }
    }
    // ---- stage B (128 rows x 32 k) ----
    if (BPRE) {
      const int rbase = wid * 16;     // 8 waves x 16 rows = 128
      gload_lds16(&WT[(size_t)(n0 + rbase + glr) * D_DIM + k0 + glc],
                  &Bs[rbase * 32]);
    } else {
      // inline f32 W transpose (fallback only): 512 slots = 32k x 16 chunks
      const int kr = tid >> 4;        // 0..31
      const int mN = tid & 15;
      const int nc = mN << 3;
      const float* src = &Wf[(size_t)(k0 + kr) * D_DIM + n0 + nc];
      f32x4 w0 = *(const f32x4*)src;
      f32x4 w1 = *(const f32x4*)(src + 4);
      const int cb = (((kr >> 3) ^ (mN & 3)) << 3) + (kr & 7);
#pragma unroll
      for (int j = 0; j < 4; ++j) {
        Bs[(nc + j) * 40 + cb] = f2bf(w0[j]);
        Bs[(nc + 4 + j) * 40 + cb] = f2bf(w1[j]);
      }
    }
    __syncthreads();  // drains vmcnt (gload_lds) + lgkm (ds_write)
    u32x4 af[4], bfr[4];
#pragma unroll
    for (int mi = 0; mi < 4; ++mi) {
      const int row = wr * 64 + mi * 16 + lr;      // 0..255
      if (AF32)
        af[mi] = *(const u32x4*)&As[row * 40 + lg * 8];
      else
        af[mi] = *(const u32x4*)&As[row * 32 + ((lg ^ (row & 3)) << 3)];
    }
#pragma unroll
    for (int ni = 0; ni < 4; ++ni) {
      const int row = wc * 64 + ni * 16 + lr;      // 0..127
      if (BPRE)
        bfr[ni] = *(const u32x4*)&Bs[row * 32 + ((lg ^ (row & 3)) << 3)];
      else
        bfr[ni] = *(const u32x4*)&Bs[row * 40 + ((lg ^ ((row >> 3) & 3)) << 3)];
    }
#pragma unroll
    for (int mi = 0; mi < 4; ++mi)
#pragma unroll
      for (int ni = 0; ni < 4; ++ni)
        acc[mi][ni] = mfma16(af[mi], bfr[ni], acc[mi][ni]);
  }

  // epilogue (C/D: col = lane&15, row = lg*4 + reg)
#pragma unroll
  for (int ni = 0; ni < 4; ++ni) {
    const int n = n0 + wc * 64 + ni * 16 + lr;
    const float bv = bias[n];
#pragma unroll
    for (int mi = 0; mi < 4; ++mi) {
      const int mb = m0 + wr * 64 + mi * 16 + lg * 4;
      float o[4];
#pragma unroll
      for (int r = 0; r < 4; ++r) o[r] = (acc[mi][ni][r] + bv) * osc;
      if (epi == 0) {
#pragma unroll
        for (int r = 0; r < 4; ++r)
          ((float*)dstv)[(size_t)(mb + r) * D_DIM + n] = o[r];
      } else {
        const unsigned int w0 = cvtpk(o[0], o[1]);
        const unsigned int w1 = cvtpk(o[2], o[3]);
        const int bb = mb >> 11, ss = mb & (S_LEN - 1);
        const int hh = n >> 6, dd = n & (DK - 1);
        if (epi == 2) {
          union { unsigned int u[2]; unsigned long long q; } pk;
          pk.u[0] = w0; pk.u[1] = w1;
          *(unsigned long long*)&((u16*)dstv)[((size_t)((bb * N_HEADS + hh) * DK + dd)) * S_LEN + ss] = pk.q;
        } else {
          u16* dp = &((u16*)dstv)[(((size_t)(bb * N_HEADS + hh) * S_LEN) + ss) * DK + dd];
          dp[0] = (u16)w0;
          dp[DK] = (u16)(w0 >> 16);
          dp[2 * DK] = (u16)w1;
          dp[3 * DK] = (u16)(w1 >> 16);
        }
      }
    }
  }
}

template <int AF32, int BPRE>
__global__ __launch_bounds__(512) void gemm_xw(const void* __restrict__ Av,
                                               const void* __restrict__ Bv,
                                               const float* __restrict__ bias,
                                               void* __restrict__ dstv,
                                               const int epi, const float osc) {
  gemm_body<AF32, BPRE>(Av, Bv, bias, dstv, epi, osc,
                        (int)blockIdx.x * 256, (int)blockIdx.y * 128);
}

// merged Q/K/V projection: z selects input/weight/bias/dst (tail overlap)
__global__ __launch_bounds__(512) void gemm_qkv(
    const float* __restrict__ q, const float* __restrict__ k,
    const float* __restrict__ v, const u16* __restrict__ WqT,
    const u16* __restrict__ WkT, const u16* __restrict__ WvT,
    const float* __restrict__ bq, const float* __restrict__ bk,
    const float* __restrict__ bv, u16* __restrict__ Qb, u16* __restrict__ Kb,
    u16* __restrict__ VTb, const float scl) {
  const int z = blockIdx.z;
  const float* A = (z == 0) ? q : (z == 1) ? k : v;
  const u16* WT = (z == 0) ? WqT : (z == 1) ? WkT : WvT;
  const float* bias = (z == 0) ? bq : (z == 1) ? bk : bv;
  u16* dst = (z == 0) ? Qb : (z == 1) ? Kb : VTb;
  gemm_body<1, 1>(A, WT, bias, dst, (z == 2) ? 2 : 1, (z == 0) ? scl : 1.0f,
                  (int)blockIdx.x * 256, (int)blockIdx.y * 128);
}

// ---- causal flash attention (round-13 verbatim: 98.5us, conflicts=0) -------
__global__ __launch_bounds__(256) void attn_kernel(const u16* __restrict__ Qb,
                                                   const u16* __restrict__ Kb,
                                                   const u16* __restrict__ VTb,
                                                   u16* __restrict__ Xb) {
  __shared__ __align__(16) u16 Vt[2][64 * 64];   // [buf][dk][kp], chunk-swizzled
  __shared__ __align__(16) u16 Pl[4][32 * 76];   // per-wave [q_local][kpos]

  const int tid = threadIdx.x;
  const int lane = tid & 63;
  const int w = tid >> 6;
  const int lr = lane & 15;
  const int lg = lane >> 4;

  // balanced XCD-pinned decode: every CU gets qi summing to 30 (68 tiles)
  const int id = (int)blockIdx.x;
  const int xcd = id & 7;
  const int slot = id >> 3;            // 0..127
  const int bh_hi = slot & 7;
  const int qpos = slot >> 3;          // 0..15
  const int grp = qpos >> 2, pos = qpos & 3;
  const int qi = (grp == 0) ? pos : (grp == 1) ? (15 - pos)
               : (grp == 2) ? (4 + pos) : (11 - pos);
  const int q0 = qi * 128;
  const int bh = (bh_hi << 3) | xcd;
  const int h = bh & (N_HEADS - 1);
  const int b = bh >> 4;

  const u16* Qh = Qb + ((size_t)bh) * S_LEN * DK;
  const u16* Kh = Kb + ((size_t)bh) * S_LEN * DK;
  const u16* VTh = VTb + ((size_t)bh) * DK * S_LEN;

  const int wrow = q0 + w * 32;
  const int nt = (q0 >> 6) + 2;

  const int vdk = tid >> 3;        // V staging rows vdk, vdk+32
  const int vc = tid & 7;          // 16B chunk

  const u32x4 ONES = {0x3F803F80u, 0x3F803F80u, 0x3F803F80u, 0x3F803F80u};

  u32x4 qf[2][2];
#pragma unroll
  for (int m = 0; m < 2; ++m)
#pragma unroll
    for (int g = 0; g < 2; ++g)
      qf[m][g] = *(const u32x4*)&Qh[(size_t)(wrow + m * 16 + lr) * DK + g * 32 + lg * 8];

  f32x4 xacc[2][4], sacc[2];
#pragma unroll
  for (int m = 0; m < 2; ++m) {
#pragma unroll
    for (int i = 0; i < 4; ++i) xacc[m][i] = (f32x4){0.f, 0.f, 0.f, 0.f};
    sacc[m] = (f32x4){0.f, 0.f, 0.f, 0.f};
  }

  // prologue: load + stage V(0) into buf0; prefetch K(0)
  u32x4 vpre[2], kreg[8];
#pragma unroll
  for (int i = 0; i < 2; ++i)
    vpre[i] = *(const u32x4*)&VTh[(size_t)(vdk + i * 32) * S_LEN + vc * 8];
#pragma unroll
  for (int g = 0; g < 2; ++g)
#pragma unroll
    for (int tt = 0; tt < 4; ++tt)
      kreg[g * 4 + tt] = *(const u32x4*)&Kh[(size_t)(tt * 16 + lr) * DK + g * 32 + lg * 8];
#pragma unroll
  for (int i = 0; i < 2; ++i) {
    const int dk = vdk + i * 32;
    *(u32x4*)&Vt[0][dk * 64 + ((vc ^ (dk & 7)) << 3)] = vpre[i];
  }

  for (int t = 0; t < nt; ++t) {
    const int kp0 = t << 6;
    const bool wact = (kp0 <= wrow + 31);
    const bool dmask = (kp0 + 63 > wrow);
    f32x4 sc[2][4];
#pragma unroll
    for (int m = 0; m < 2; ++m)
#pragma unroll
      for (int tt = 0; tt < 4; ++tt) sc[m][tt] = (f32x4){0.f, 0.f, 0.f, 0.f};
    if (wact) {
      __builtin_amdgcn_s_setprio(1);
#pragma unroll
      for (int g = 0; g < 2; ++g)
#pragma unroll
        for (int tt = 0; tt < 4; ++tt) {
          sc[0][tt] = mfma16(kreg[g * 4 + tt], qf[0][g], sc[0][tt]);  // swapped
          sc[1][tt] = mfma16(kreg[g * 4 + tt], qf[1][g], sc[1][tt]);
        }
      __builtin_amdgcn_s_setprio(0);
      // softmax: p = exp2(s); mask only on diagonal tile; cvtpk + b64 writes
#pragma unroll
      for (int m = 0; m < 2; ++m) {
        const int qre = wrow + m * 16 + lr;
        float pv[4][4];
        if (dmask) {
#pragma unroll
          for (int tt = 0; tt < 4; ++tt)
#pragma unroll
            for (int r = 0; r < 4; ++r) {
              const int kpe = kp0 + tt * 16 + lg * 4 + r;
              float s = sc[m][tt][r];
              if (kpe > qre) s = -1e30f;
              pv[tt][r] = exp2f(s);
            }
        } else {
#pragma unroll
          for (int tt = 0; tt < 4; ++tt)
#pragma unroll
            for (int r = 0; r < 4; ++r) pv[tt][r] = exp2f(sc[m][tt][r]);
        }
#pragma unroll
        for (int tt = 0; tt < 4; ++tt) {
          uint2 pw;
          pw.x = cvtpk(pv[tt][0], pv[tt][1]);
          pw.y = cvtpk(pv[tt][2], pv[tt][3]);
          *(uint2*)&Pl[w][(m * 16 + lr) * 76 + tt * 16 + lg * 4] = pw;
        }
      }
    }
    __syncthreads();  // drains Pl + prior-tile staging; no fresh loads pending
    // prefetch K(t+1), V(t+1) AFTER the barrier
    const bool pre = (t + 1 < nt);
    if (pre) {
      const int kn = (t + 1) << 6;
#pragma unroll
      for (int i = 0; i < 2; ++i)
        vpre[i] = *(const u32x4*)&VTh[(size_t)(vdk + i * 32) * S_LEN + kn + vc * 8];
#pragma unroll
      for (int g = 0; g < 2; ++g)
#pragma unroll
        for (int tt = 0; tt < 4; ++tt)
          kreg[g * 4 + tt] = *(const u32x4*)&Kh[(size_t)(kn + tt * 16 + lr) * DK + g * 32 + lg * 8];
    }
    if (wact) {
      u32x4 pf[2][2];
#pragma unroll
      for (int m = 0; m < 2; ++m) {
        pf[m][0] = *(const u32x4*)&Pl[w][(m * 16 + lr) * 76 + lg * 8];
        pf[m][1] = *(const u32x4*)&Pl[w][(m * 16 + lr) * 76 + 32 + lg * 8];
      }
      __builtin_amdgcn_s_setprio(1);
#pragma unroll
      for (int db = 0; db < 4; ++db) {
        const int vr = db * 16 + lr;
        u32x4 vf0 = *(const u32x4*)&Vt[t & 1][vr * 64 + ((lg ^ (vr & 7)) << 3)];
        u32x4 vf1 = *(const u32x4*)&Vt[t & 1][vr * 64 + (((lg ^ 4) ^ (vr & 7)) << 3)];
#pragma unroll
        for (int m = 0; m < 2; ++m) {
          xacc[m][db] = mfma16(pf[m][0], vf0, xacc[m][db]);
          xacc[m][db] = mfma16(pf[m][1], vf1, xacc[m][db]);
        }
      }
      // row-sums on the MFMA pipe
#pragma unroll
      for (int m = 0; m < 2; ++m) {
        sacc[m] = mfma16(pf[m][0], ONES, sacc[m]);
        sacc[m] = mfma16(pf[m][1], ONES, sacc[m]);
      }
      __builtin_amdgcn_s_setprio(0);
    }
    if (pre) {
#pragma unroll
      for (int i = 0; i < 2; ++i) {
        const int dk = vdk + i * 32;
        *(u32x4*)&Vt[(t + 1) & 1][dk * 64 + ((vc ^ (dk & 7)) << 3)] = vpre[i];
      }
    }
  }

#pragma unroll
  for (int m = 0; m < 2; ++m)
#pragma unroll
    for (int r = 0; r < 4; ++r) {
      const float inv = 1.0f / fmaxf(sacc[m][r], 1e-30f);
      const int srow = wrow + m * 16 + lg * 4 + r;
      const size_t base = ((size_t)b * S_LEN + srow) * D_DIM + h * DK;
      const unsigned int w0 = cvtpk(xacc[m][0][r] * inv, xacc[m][1][r] * inv);
      const unsigned int w1 = cvtpk(xacc[m][2][r] * inv, xacc[m][3][r] * inv);
      Xb[base + 0 * 16 + lr] = (u16)w0;
      Xb[base + 1 * 16 + lr] = (u16)(w0 >> 16);
      Xb[base + 2 * 16 + lr] = (u16)w1;
      Xb[base + 3 * 16 + lr] = (u16)(w1 >> 16);
    }
}

// ---- launcher ---------------------------------------------------------------
// d_out holds Qb+Kb (bf16, 33.55MB = out_size*4B). ws: VTb + Xb (+4x WT bf16).
extern "C" void kernel_launch(void* const* d_in, const int* in_sizes, int n_in,
                              void* d_out, int out_size, void* d_ws, size_t ws_size,
                              hipStream_t stream) {
  const float* q = (const float*)d_in[0];
  const float* k = (const float*)d_in[1];
  const float* v = (const float*)d_in[2];
  const float* Wq = (const float*)d_in[4];  const float* bq = (const float*)d_in[5];
  const float* Wk = (const float*)d_in[6];  const float* bk = (const float*)d_in[7];
  const float* Wv = (const float*)d_in[8];  const float* bv = (const float*)d_in[9];
  const float* Wo = (const float*)d_in[10]; const float* bo = (const float*)d_in[11];

  u16* Qb = (u16*)d_out;
  u16* Kb = Qb + (8u << 20);
  u16* VTb = (u16*)d_ws;
  u16* Xb = VTb + (8u << 20);

  const float scl = 0.125f * 1.4426950408889634f;  // 1/sqrt(DK) * log2(e)
  const dim3 tb(256);
  const dim3 tg(512);
  const size_t need = ((size_t)(8u << 20)) * 2 * 2 + 4 * ((size_t)(1u << 20)) * 2;

  if (ws_size >= need) {
    u16* WqT = Xb + (8u << 20);
    u16* WkT = WqT + (1u << 20);
    u16* WvT = WkT + (1u << 20);
    u16* WoT = WvT + (1u << 20);
    transpose_all<<<dim3(32, 32, 4), tb, 0, stream>>>(Wq, Wk, Wv, Wo, WqT, WkT, WvT, WoT);
    gemm_qkv<<<dim3(32, 8, 3), tg, 0, stream>>>(q, k, v, WqT, WkT, WvT,
                                                bq, bk, bv, Qb, Kb, VTb, scl);
    attn_kernel<<<dim3(1024), tb, 0, stream>>>(Qb, Kb, VTb, Xb);
    gemm_xw<0, 1><<<dim3(32, 8), tg, 0, stream>>>(Xb, WoT, bo, d_out, 0, 1.0f);
  } else {
    gemm_xw<1, 0><<<dim3(32, 8), tg, 0, stream>>>(q, Wq, bq, Qb, 1, scl);
    gemm_xw<1, 0><<<dim3(32, 8), tg, 0, stream>>>(k, Wk, bk, Kb, 1, 1.0f);
    gemm_xw<1, 0><<<dim3(32, 8), tg, 0, stream>>>(v, Wv, bv, VTb, 2, 1.0f);
    attn_kernel<<<dim3(1024), tb, 0, stream>>>(Qb, Kb, VTb, Xb);
    gemm_xw<0, 0><<<dim3(32, 8), tg, 0, stream>>>(Xb, Wo, bo, d_out, 0, 1.0f);
  }
}

// Round 20
// 216.991 us; speedup vs baseline: 1.0890x; 1.0890x over previous
//
#include <hip/hip_runtime.h>

typedef unsigned short u16;
typedef __attribute__((ext_vector_type(4))) float f32x4;
typedef __attribute__((ext_vector_type(8))) __bf16 bf16x8;
typedef __attribute__((ext_vector_type(4))) unsigned int u32x4;

#define S_LEN 2048
#define D_DIM 1024
#define N_HEADS 16
#define DK 64
#define B_SZ 4

__device__ __forceinline__ u16 f2bf(float f) {
  unsigned int u = __float_as_uint(f);
  unsigned int r = (u + 0x7FFFu + ((u >> 16) & 1u)) >> 16;
  return (u16)r;
}
__device__ __forceinline__ unsigned int cvtpk(float a, float b) {
  unsigned int r;
  asm("v_cvt_pk_bf16_f32 %0, %1, %2" : "=v"(r) : "v"(a), "v"(b));
  return r;  // low16 = bf16(a), high16 = bf16(b)
}
__device__ __forceinline__ f32x4 mfma16(u32x4 a, u32x4 b, f32x4 c) {
  return __builtin_amdgcn_mfma_f32_16x16x32_bf16(
      __builtin_bit_cast(bf16x8, a), __builtin_bit_cast(bf16x8, b), c, 0, 0, 0);
}
// async global->LDS, 16B/lane; LDS dest = wave-uniform base + lane*16
__device__ __forceinline__ void gload_lds16(const void* g, void* l) {
  __builtin_amdgcn_global_load_lds(
      (const __attribute__((address_space(1))) void*)g,
      (__attribute__((address_space(3))) void*)l, 16, 0, 0);
}

// ---- fused weight transposes: WT[n][k] (bf16) = W[k][n] (f32) --------------
__global__ __launch_bounds__(256) void transpose_all(
    const float* __restrict__ W0, const float* __restrict__ W1,
    const float* __restrict__ W2, const float* __restrict__ W3,
    u16* __restrict__ T0, u16* __restrict__ T1,
    u16* __restrict__ T2, u16* __restrict__ T3) {
  __shared__ float tb[32][33];
  const int z = blockIdx.z;
  const float* W = (z == 0) ? W0 : (z == 1) ? W1 : (z == 2) ? W2 : W3;
  u16* WT = (z == 0) ? T0 : (z == 1) ? T1 : (z == 2) ? T2 : T3;
  const int tx = threadIdx.x & 31;
  const int ty0 = (threadIdx.x >> 5) << 2;
  const int bn = blockIdx.x << 5;
  const int bk = blockIdx.y << 5;
#pragma unroll
  for (int i = 0; i < 4; ++i)
    tb[ty0 + i][tx] = W[(size_t)(bk + ty0 + i) * D_DIM + bn + tx];
  __syncthreads();
#pragma unroll
  for (int i = 0; i < 4; ++i)
    WT[(size_t)(bn + ty0 + i) * D_DIM + bk + tx] = f2bf(tb[tx][ty0 + i]);
}

// ---- f32 -> bf16 conversion of q/k/v (8 elems/thread, RTNE via cvtpk) ------
__global__ __launch_bounds__(256) void convert3(
    const float* __restrict__ q, const float* __restrict__ k,
    const float* __restrict__ v, u16* __restrict__ qb, u16* __restrict__ kb,
    u16* __restrict__ vb) {
  const int z = blockIdx.z;
  const float* src = (z == 0) ? q : (z == 1) ? k : v;
  u16* dst = (z == 0) ? qb : (z == 1) ? kb : vb;
  const size_t i = ((size_t)blockIdx.x * 256 + threadIdx.x) * 8;
  f32x4 a0 = *(const f32x4*)&src[i];
  f32x4 a1 = *(const f32x4*)&src[i + 4];
  u32x4 pk = (u32x4){cvtpk(a0[0], a0[1]), cvtpk(a0[2], a0[3]),
                     cvtpk(a1[0], a1[1]), cvtpk(a1[2], a1[3])};
  *(u32x4*)&dst[i] = pk;
}

// ---- GEMM body: round-13/15 proven structure (timed-best 206.5us) ----------
// 128x128 tile, BK=32, 4 waves (2x2). bf16 operands staged via gload_lds into
// linear [128][32] (source chunk ^= row&3, read same XOR). AF32 A-path:
// reg+cvtpk into As[128][40] (2-way writes = free).
template <int AF32, int BPRE>
__device__ __forceinline__ void gemm_body(const void* __restrict__ Av,
                                          const void* __restrict__ Bv,
                                          const float* __restrict__ bias,
                                          void* __restrict__ dstv,
                                          const int epi, const float osc,
                                          const int m0, const int n0) {
  __shared__ __align__(16) u16 As[128 * 40];
  __shared__ __align__(16) u16 Bs[128 * 40];
  const int tid = threadIdx.x;
  const int lane = tid & 63;
  const int wid = tid >> 6;
  const int wr = wid >> 1, wc = wid & 1;
  const int lr = lane & 15, lg = lane >> 4;

  const float* Xf = (const float*)Av;
  const u16* Xh = (const u16*)Av;
  const float* Wf = (const float*)Bv;
  const u16* WT = (const u16*)Bv;

  f32x4 acc[4][4];
#pragma unroll
  for (int i = 0; i < 4; ++i)
#pragma unroll
    for (int j = 0; j < 4; ++j) acc[i][j] = (f32x4){0.f, 0.f, 0.f, 0.f};

  const int srow = tid >> 2;
  const int sko = (tid & 3) << 3;
  const int glr = lane >> 2;                       // 0..15
  const int glc = ((lane & 3) ^ (glr & 3)) << 3;   // pre-swizzled chunk (elems)

  for (int k0 = 0; k0 < D_DIM; k0 += 32) {
    __syncthreads();
    if (AF32) {
#pragma unroll
      for (int i = 0; i < 2; ++i) {
        const int row = srow + i * 64;
        const float* src = &Xf[(size_t)(m0 + row) * D_DIM + k0 + sko];
        f32x4 a0 = *(const f32x4*)src;
        f32x4 a1 = *(const f32x4*)(src + 4);
        u32x4 pk = (u32x4){cvtpk(a0[0], a0[1]), cvtpk(a0[2], a0[3]),
                           cvtpk(a1[0], a1[1]), cvtpk(a1[2], a1[3])};
        *(u32x4*)&As[row * 40 + sko] = pk;
      }
    } else {
#pragma unroll
      for (int j = 0; j < 2; ++j) {
        const int rbase = wid * 32 + j * 16;
        gload_lds16(&Xh[(size_t)(m0 + rbase + glr) * D_DIM + k0 + glc],
                    &As[rbase * 32]);
      }
    }
    if (BPRE) {
#pragma unroll
      for (int j = 0; j < 2; ++j) {
        const int rbase = wid * 32 + j * 16;
        gload_lds16(&WT[(size_t)(n0 + rbase + glr) * D_DIM + k0 + glc],
                    &Bs[rbase * 32]);
      }
    } else {
#pragma unroll
      for (int i = 0; i < 2; ++i) {
        const int s = tid + (i << 8);
        const int kr = s >> 4;
        const int mN = s & 15;
        const int nc = mN << 3;
        const float* src = &Wf[(size_t)(k0 + kr) * D_DIM + n0 + nc];
        f32x4 w0 = *(const f32x4*)src;
        f32x4 w1 = *(const f32x4*)(src + 4);
        const int cb = (((kr >> 3) ^ (mN & 3)) << 3) + (kr & 7);
#pragma unroll
        for (int j = 0; j < 4; ++j) {
          Bs[(nc + j) * 40 + cb] = f2bf(w0[j]);
          Bs[(nc + 4 + j) * 40 + cb] = f2bf(w1[j]);
        }
      }
    }
    __syncthreads();  // drains vmcnt (gload_lds) + lgkm (ds_write)
    u32x4 af[4], bfr[4];
#pragma unroll
    for (int mi = 0; mi < 4; ++mi) {
      const int row = wr * 64 + mi * 16 + lr;
      if (AF32)
        af[mi] = *(const u32x4*)&As[row * 40 + lg * 8];
      else
        af[mi] = *(const u32x4*)&As[row * 32 + ((lg ^ (row & 3)) << 3)];
    }
#pragma unroll
    for (int ni = 0; ni < 4; ++ni) {
      const int row = wc * 64 + ni * 16 + lr;
      if (BPRE)
        bfr[ni] = *(const u32x4*)&Bs[row * 32 + ((lg ^ (row & 3)) << 3)];
      else
        bfr[ni] = *(const u32x4*)&Bs[row * 40 + ((lg ^ ((row >> 3) & 3)) << 3)];
    }
#pragma unroll
    for (int mi = 0; mi < 4; ++mi)
#pragma unroll
      for (int ni = 0; ni < 4; ++ni)
        acc[mi][ni] = mfma16(af[mi], bfr[ni], acc[mi][ni]);
  }

  // epilogue (C/D: col = lane&15, row = lg*4 + reg)
#pragma unroll
  for (int ni = 0; ni < 4; ++ni) {
    const int n = n0 + wc * 64 + ni * 16 + lr;
    const float bv = bias[n];
#pragma unroll
    for (int mi = 0; mi < 4; ++mi) {
      const int mb = m0 + wr * 64 + mi * 16 + lg * 4;
      float o[4];
#pragma unroll
      for (int r = 0; r < 4; ++r) o[r] = (acc[mi][ni][r] + bv) * osc;
      if (epi == 0) {
#pragma unroll
        for (int r = 0; r < 4; ++r)
          ((float*)dstv)[(size_t)(mb + r) * D_DIM + n] = o[r];
      } else {
        const unsigned int w0 = cvtpk(o[0], o[1]);
        const unsigned int w1 = cvtpk(o[2], o[3]);
        const int bb = mb >> 11, ss = mb & (S_LEN - 1);
        const int hh = n >> 6, dd = n & (DK - 1);
        if (epi == 2) {
          union { unsigned int u[2]; unsigned long long q; } pk;
          pk.u[0] = w0; pk.u[1] = w1;
          *(unsigned long long*)&((u16*)dstv)[((size_t)((bb * N_HEADS + hh) * DK + dd)) * S_LEN + ss] = pk.q;
        } else {
          u16* dp = &((u16*)dstv)[(((size_t)(bb * N_HEADS + hh) * S_LEN) + ss) * DK + dd];
          dp[0] = (u16)w0;
          dp[DK] = (u16)(w0 >> 16);
          dp[2 * DK] = (u16)w1;
          dp[3 * DK] = (u16)(w1 >> 16);
        }
      }
    }
  }
}

template <int AF32, int BPRE>
__global__ __launch_bounds__(256) void gemm_xw(const void* __restrict__ Av,
                                               const void* __restrict__ Bv,
                                               const float* __restrict__ bias,
                                               void* __restrict__ dstv,
                                               const int epi, const float osc) {
  gemm_body<AF32, BPRE>(Av, Bv, bias, dstv, epi, osc,
                        (int)blockIdx.x * 128, (int)blockIdx.y * 128);
}

// merged Q/K/V projection, f32-A path (tier-2 fallback)
__global__ __launch_bounds__(256) void gemm_qkv(
    const float* __restrict__ q, const float* __restrict__ k,
    const float* __restrict__ v, const u16* __restrict__ WqT,
    const u16* __restrict__ WkT, const u16* __restrict__ WvT,
    const float* __restrict__ bq, const float* __restrict__ bk,
    const float* __restrict__ bv, u16* __restrict__ Qb, u16* __restrict__ Kb,
    u16* __restrict__ VTb, const float scl) {
  const int z = blockIdx.z;
  const float* A = (z == 0) ? q : (z == 1) ? k : v;
  const u16* WT = (z == 0) ? WqT : (z == 1) ? WkT : WvT;
  const float* bias = (z == 0) ? bq : (z == 1) ? bk : bv;
  u16* dst = (z == 0) ? Qb : (z == 1) ? Kb : VTb;
  gemm_body<1, 1>(A, WT, bias, dst, (z == 2) ? 2 : 1, (z == 0) ? scl : 1.0f,
                  (int)blockIdx.x * 128, (int)blockIdx.y * 128);
}

// merged Q/K/V projection, bf16-A both-gload path (oproj-proven ~860 TF)
__global__ __launch_bounds__(256) void gemm_qkv_b(
    const u16* __restrict__ qb, const u16* __restrict__ kb,
    const u16* __restrict__ vb, const u16* __restrict__ WqT,
    const u16* __restrict__ WkT, const u16* __restrict__ WvT,
    const float* __restrict__ bq, const float* __restrict__ bk,
    const float* __restrict__ bv, u16* __restrict__ Qb, u16* __restrict__ Kb,
    u16* __restrict__ VTb, const float scl) {
  const int z = blockIdx.z;
  const u16* A = (z == 0) ? qb : (z == 1) ? kb : vb;
  const u16* WT = (z == 0) ? WqT : (z == 1) ? WkT : WvT;
  const float* bias = (z == 0) ? bq : (z == 1) ? bk : bv;
  u16* dst = (z == 0) ? Qb : (z == 1) ? Kb : VTb;
  gemm_body<0, 1>(A, WT, bias, dst, (z == 2) ? 2 : 1, (z == 0) ? scl : 1.0f,
                  (int)blockIdx.x * 128, (int)blockIdx.y * 128);
}

// ---- causal flash attention (round-13 verbatim: 98.5us, conflicts=0) -------
__global__ __launch_bounds__(256) void attn_kernel(const u16* __restrict__ Qb,
                                                   const u16* __restrict__ Kb,
                                                   const u16* __restrict__ VTb,
                                                   u16* __restrict__ Xb) {
  __shared__ __align__(16) u16 Vt[2][64 * 64];   // [buf][dk][kp], chunk-swizzled
  __shared__ __align__(16) u16 Pl[4][32 * 76];   // per-wave [q_local][kpos]

  const int tid = threadIdx.x;
  const int lane = tid & 63;
  const int w = tid >> 6;
  const int lr = lane & 15;
  const int lg = lane >> 4;

  // balanced XCD-pinned decode: every CU gets qi summing to 30 (68 tiles)
  const int id = (int)blockIdx.x;
  const int xcd = id & 7;
  const int slot = id >> 3;            // 0..127
  const int bh_hi = slot & 7;
  const int qpos = slot >> 3;          // 0..15
  const int grp = qpos >> 2, pos = qpos & 3;
  const int qi = (grp == 0) ? pos : (grp == 1) ? (15 - pos)
               : (grp == 2) ? (4 + pos) : (11 - pos);
  const int q0 = qi * 128;
  const int bh = (bh_hi << 3) | xcd;
  const int h = bh & (N_HEADS - 1);
  const int b = bh >> 4;

  const u16* Qh = Qb + ((size_t)bh) * S_LEN * DK;
  const u16* Kh = Kb + ((size_t)bh) * S_LEN * DK;
  const u16* VTh = VTb + ((size_t)bh) * DK * S_LEN;

  const int wrow = q0 + w * 32;
  const int nt = (q0 >> 6) + 2;

  const int vdk = tid >> 3;        // V staging rows vdk, vdk+32
  const int vc = tid & 7;          // 16B chunk

  const u32x4 ONES = {0x3F803F80u, 0x3F803F80u, 0x3F803F80u, 0x3F803F80u};

  u32x4 qf[2][2];
#pragma unroll
  for (int m = 0; m < 2; ++m)
#pragma unroll
    for (int g = 0; g < 2; ++g)
      qf[m][g] = *(const u32x4*)&Qh[(size_t)(wrow + m * 16 + lr) * DK + g * 32 + lg * 8];

  f32x4 xacc[2][4], sacc[2];
#pragma unroll
  for (int m = 0; m < 2; ++m) {
#pragma unroll
    for (int i = 0; i < 4; ++i) xacc[m][i] = (f32x4){0.f, 0.f, 0.f, 0.f};
    sacc[m] = (f32x4){0.f, 0.f, 0.f, 0.f};
  }

  // prologue: load + stage V(0) into buf0; prefetch K(0)
  u32x4 vpre[2], kreg[8];
#pragma unroll
  for (int i = 0; i < 2; ++i)
    vpre[i] = *(const u32x4*)&VTh[(size_t)(vdk + i * 32) * S_LEN + vc * 8];
#pragma unroll
  for (int g = 0; g < 2; ++g)
#pragma unroll
    for (int tt = 0; tt < 4; ++tt)
      kreg[g * 4 + tt] = *(const u32x4*)&Kh[(size_t)(tt * 16 + lr) * DK + g * 32 + lg * 8];
#pragma unroll
  for (int i = 0; i < 2; ++i) {
    const int dk = vdk + i * 32;
    *(u32x4*)&Vt[0][dk * 64 + ((vc ^ (dk & 7)) << 3)] = vpre[i];
  }

  for (int t = 0; t < nt; ++t) {
    const int kp0 = t << 6;
    const bool wact = (kp0 <= wrow + 31);
    const bool dmask = (kp0 + 63 > wrow);
    f32x4 sc[2][4];
#pragma unroll
    for (int m = 0; m < 2; ++m)
#pragma unroll
      for (int tt = 0; tt < 4; ++tt) sc[m][tt] = (f32x4){0.f, 0.f, 0.f, 0.f};
    if (wact) {
      __builtin_amdgcn_s_setprio(1);
#pragma unroll
      for (int g = 0; g < 2; ++g)
#pragma unroll
        for (int tt = 0; tt < 4; ++tt) {
          sc[0][tt] = mfma16(kreg[g * 4 + tt], qf[0][g], sc[0][tt]);  // swapped
          sc[1][tt] = mfma16(kreg[g * 4 + tt], qf[1][g], sc[1][tt]);
        }
      __builtin_amdgcn_s_setprio(0);
      // softmax: p = exp2(s); mask only on diagonal tile; cvtpk + b64 writes
#pragma unroll
      for (int m = 0; m < 2; ++m) {
        const int qre = wrow + m * 16 + lr;
        float pv[4][4];
        if (dmask) {
#pragma unroll
          for (int tt = 0; tt < 4; ++tt)
#pragma unroll
            for (int r = 0; r < 4; ++r) {
              const int kpe = kp0 + tt * 16 + lg * 4 + r;
              float s = sc[m][tt][r];
              if (kpe > qre) s = -1e30f;
              pv[tt][r] = exp2f(s);
            }
        } else {
#pragma unroll
          for (int tt = 0; tt < 4; ++tt)
#pragma unroll
            for (int r = 0; r < 4; ++r) pv[tt][r] = exp2f(sc[m][tt][r]);
        }
#pragma unroll
        for (int tt = 0; tt < 4; ++tt) {
          uint2 pw;
          pw.x = cvtpk(pv[tt][0], pv[tt][1]);
          pw.y = cvtpk(pv[tt][2], pv[tt][3]);
          *(uint2*)&Pl[w][(m * 16 + lr) * 76 + tt * 16 + lg * 4] = pw;
        }
      }
    }
    __syncthreads();  // drains Pl + prior-tile staging; no fresh loads pending
    // prefetch K(t+1), V(t+1) AFTER the barrier
    const bool pre = (t + 1 < nt);
    if (pre) {
      const int kn = (t + 1) << 6;
#pragma unroll
      for (int i = 0; i < 2; ++i)
        vpre[i] = *(const u32x4*)&VTh[(size_t)(vdk + i * 32) * S_LEN + kn + vc * 8];
#pragma unroll
      for (int g = 0; g < 2; ++g)
#pragma unroll
        for (int tt = 0; tt < 4; ++tt)
          kreg[g * 4 + tt] = *(const u32x4*)&Kh[(size_t)(kn + tt * 16 + lr) * DK + g * 32 + lg * 8];
    }
    if (wact) {
      u32x4 pf[2][2];
#pragma unroll
      for (int m = 0; m < 2; ++m) {
        pf[m][0] = *(const u32x4*)&Pl[w][(m * 16 + lr) * 76 + lg * 8];
        pf[m][1] = *(const u32x4*)&Pl[w][(m * 16 + lr) * 76 + 32 + lg * 8];
      }
      __builtin_amdgcn_s_setprio(1);
#pragma unroll
      for (int db = 0; db < 4; ++db) {
        const int vr = db * 16 + lr;
        u32x4 vf0 = *(const u32x4*)&Vt[t & 1][vr * 64 + ((lg ^ (vr & 7)) << 3)];
        u32x4 vf1 = *(const u32x4*)&Vt[t & 1][vr * 64 + (((lg ^ 4) ^ (vr & 7)) << 3)];
#pragma unroll
        for (int m = 0; m < 2; ++m) {
          xacc[m][db] = mfma16(pf[m][0], vf0, xacc[m][db]);
          xacc[m][db] = mfma16(pf[m][1], vf1, xacc[m][db]);
        }
      }
      // row-sums on the MFMA pipe
#pragma unroll
      for (int m = 0; m < 2; ++m) {
        sacc[m] = mfma16(pf[m][0], ONES, sacc[m]);
        sacc[m] = mfma16(pf[m][1], ONES, sacc[m]);
      }
      __builtin_amdgcn_s_setprio(0);
    }
    if (pre) {
#pragma unroll
      for (int i = 0; i < 2; ++i) {
        const int dk = vdk + i * 32;
        *(u32x4*)&Vt[(t + 1) & 1][dk * 64 + ((vc ^ (dk & 7)) << 3)] = vpre[i];
      }
    }
  }

#pragma unroll
  for (int m = 0; m < 2; ++m)
#pragma unroll
    for (int r = 0; r < 4; ++r) {
      const float inv = 1.0f / fmaxf(sacc[m][r], 1e-30f);
      const int srow = wrow + m * 16 + lg * 4 + r;
      const size_t base = ((size_t)b * S_LEN + srow) * D_DIM + h * DK;
      const unsigned int w0 = cvtpk(xacc[m][0][r] * inv, xacc[m][1][r] * inv);
      const unsigned int w1 = cvtpk(xacc[m][2][r] * inv, xacc[m][3][r] * inv);
      Xb[base + 0 * 16 + lr] = (u16)w0;
      Xb[base + 1 * 16 + lr] = (u16)(w0 >> 16);
      Xb[base + 2 * 16 + lr] = (u16)w1;
      Xb[base + 3 * 16 + lr] = (u16)(w1 >> 16);
    }
}

// ---- launcher ---------------------------------------------------------------
// d_out holds Qb+Kb (bf16, 33.55MB = out_size*4B).
// ws tiers: [VTb 16.78][Xb 16.78][4x WT 8.39][qb/kb/vb 50.33] = 92.3MB (tier1)
//           first 41.94MB only (tier2, round-15 path) ; else inline-W fallback.
extern "C" void kernel_launch(void* const* d_in, const int* in_sizes, int n_in,
                              void* d_out, int out_size, void* d_ws, size_t ws_size,
                              hipStream_t stream) {
  const float* q = (const float*)d_in[0];
  const float* k = (const float*)d_in[1];
  const float* v = (const float*)d_in[2];
  const float* Wq = (const float*)d_in[4];  const float* bq = (const float*)d_in[5];
  const float* Wk = (const float*)d_in[6];  const float* bk = (const float*)d_in[7];
  const float* Wv = (const float*)d_in[8];  const float* bv = (const float*)d_in[9];
  const float* Wo = (const float*)d_in[10]; const float* bo = (const float*)d_in[11];

  u16* Qb = (u16*)d_out;
  u16* Kb = Qb + (8u << 20);
  u16* VTb = (u16*)d_ws;
  u16* Xb = VTb + (8u << 20);

  const float scl = 0.125f * 1.4426950408889634f;  // 1/sqrt(DK) * log2(e)
  const dim3 tb(256);
  const size_t need1 = ((size_t)(8u << 20)) * 2 * 2 + 4 * ((size_t)(1u << 20)) * 2;
  const size_t need2 = need1 + 3 * ((size_t)(8u << 20)) * 2;

  if (ws_size >= need1) {
    u16* WqT = Xb + (8u << 20);
    u16* WkT = WqT + (1u << 20);
    u16* WvT = WkT + (1u << 20);
    u16* WoT = WvT + (1u << 20);
    transpose_all<<<dim3(32, 32, 4), tb, 0, stream>>>(Wq, Wk, Wv, Wo, WqT, WkT, WvT, WoT);
    if (ws_size >= need2) {
      u16* qb = WoT + (1u << 20);
      u16* kb = qb + (8u << 20);
      u16* vb = kb + (8u << 20);
      convert3<<<dim3(4096, 1, 3), tb, 0, stream>>>(q, k, v, qb, kb, vb);
      gemm_qkv_b<<<dim3(64, 8, 3), tb, 0, stream>>>(qb, kb, vb, WqT, WkT, WvT,
                                                    bq, bk, bv, Qb, Kb, VTb, scl);
    } else {
      gemm_qkv<<<dim3(64, 8, 3), tb, 0, stream>>>(q, k, v, WqT, WkT, WvT,
                                                  bq, bk, bv, Qb, Kb, VTb, scl);
    }
    attn_kernel<<<dim3(1024), tb, 0, stream>>>(Qb, Kb, VTb, Xb);
    gemm_xw<0, 1><<<dim3(64, 8), tb, 0, stream>>>(Xb, WoT, bo, d_out, 0, 1.0f);
  } else {
    gemm_xw<1, 0><<<dim3(64, 8), tb, 0, stream>>>(q, Wq, bq, Qb, 1, scl);
    gemm_xw<1, 0><<<dim3(64, 8), tb, 0, stream>>>(k, Wk, bk, Kb, 1, 1.0f);
    gemm_xw<1, 0><<<dim3(64, 8), tb, 0, stream>>>(v, Wv, bv, VTb, 2, 1.0f);
    attn_kernel<<<dim3(1024), tb, 0, stream>>>(Qb, Kb, VTb, Xb);
    gemm_xw<0, 0><<<dim3(64, 8), tb, 0, stream>>>(Xb, Wo, bo, d_out, 0, 1.0f);
  }
}

// Round 21
// 207.031 us; speedup vs baseline: 1.1414x; 1.0481x over previous
//
#include <hip/hip_runtime.h>

typedef unsigned short u16;
typedef __attribute__((ext_vector_type(4))) float f32x4;
typedef __attribute__((ext_vector_type(8))) __bf16 bf16x8;
typedef __attribute__((ext_vector_type(4))) unsigned int u32x4;

#define S_LEN 2048
#define D_DIM 1024
#define N_HEADS 16
#define DK 64
#define B_SZ 4

__device__ __forceinline__ u16 f2bf(float f) {
  unsigned int u = __float_as_uint(f);
  unsigned int r = (u + 0x7FFFu + ((u >> 16) & 1u)) >> 16;
  return (u16)r;
}
__device__ __forceinline__ unsigned int cvtpk(float a, float b) {
  unsigned int r;
  asm("v_cvt_pk_bf16_f32 %0, %1, %2" : "=v"(r) : "v"(a), "v"(b));
  return r;  // low16 = bf16(a), high16 = bf16(b)
}
__device__ __forceinline__ f32x4 mfma16(u32x4 a, u32x4 b, f32x4 c) {
  return __builtin_amdgcn_mfma_f32_16x16x32_bf16(
      __builtin_bit_cast(bf16x8, a), __builtin_bit_cast(bf16x8, b), c, 0, 0, 0);
}
// async global->LDS, 16B/lane; LDS dest = wave-uniform base + lane*16
__device__ __forceinline__ void gload_lds16(const void* g, void* l) {
  __builtin_amdgcn_global_load_lds(
      (const __attribute__((address_space(1))) void*)g,
      (__attribute__((address_space(3))) void*)l, 16, 0, 0);
}

// ---- fused weight transposes: WT[n][k] (bf16) = W[k][n] (f32) --------------
__global__ __launch_bounds__(256) void transpose_all(
    const float* __restrict__ W0, const float* __restrict__ W1,
    const float* __restrict__ W2, const float* __restrict__ W3,
    u16* __restrict__ T0, u16* __restrict__ T1,
    u16* __restrict__ T2, u16* __restrict__ T3) {
  __shared__ float tb[32][33];
  const int z = blockIdx.z;
  const float* W = (z == 0) ? W0 : (z == 1) ? W1 : (z == 2) ? W2 : W3;
  u16* WT = (z == 0) ? T0 : (z == 1) ? T1 : (z == 2) ? T2 : T3;
  const int tx = threadIdx.x & 31;
  const int ty0 = (threadIdx.x >> 5) << 2;
  const int bn = blockIdx.x << 5;
  const int bk = blockIdx.y << 5;
#pragma unroll
  for (int i = 0; i < 4; ++i)
    tb[ty0 + i][tx] = W[(size_t)(bk + ty0 + i) * D_DIM + bn + tx];
  __syncthreads();
#pragma unroll
  for (int i = 0; i < 4; ++i)
    WT[(size_t)(bn + ty0 + i) * D_DIM + bk + tx] = f2bf(tb[tx][ty0 + i]);
}

// ---- GEMM body (round-13 structure; timed-best 206.5us configuration) ------
template <int AF32, int BPRE>
__device__ __forceinline__ void gemm_body(const void* __restrict__ Av,
                                          const void* __restrict__ Bv,
                                          const float* __restrict__ bias,
                                          void* __restrict__ dstv,
                                          const int epi, const float osc,
                                          const int m0, const int n0) {
  __shared__ __align__(16) u16 As[128 * 40];
  __shared__ __align__(16) u16 Bs[128 * 40];
  const int tid = threadIdx.x;
  const int lane = tid & 63;
  const int wid = tid >> 6;
  const int wr = wid >> 1, wc = wid & 1;
  const int lr = lane & 15, lg = lane >> 4;

  const float* Xf = (const float*)Av;
  const u16* Xh = (const u16*)Av;
  const float* Wf = (const float*)Bv;
  const u16* WT = (const u16*)Bv;

  f32x4 acc[4][4];
#pragma unroll
  for (int i = 0; i < 4; ++i)
#pragma unroll
    for (int j = 0; j < 4; ++j) acc[i][j] = (f32x4){0.f, 0.f, 0.f, 0.f};

  const int srow = tid >> 2;
  const int sko = (tid & 3) << 3;
  const int glr = lane >> 2;                       // 0..15
  const int glc = ((lane & 3) ^ (glr & 3)) << 3;   // pre-swizzled chunk (elems)

  for (int k0 = 0; k0 < D_DIM; k0 += 32) {
    __syncthreads();
    if (AF32) {
#pragma unroll
      for (int i = 0; i < 2; ++i) {
        const int row = srow + i * 64;
        const float* src = &Xf[(size_t)(m0 + row) * D_DIM + k0 + sko];
        f32x4 a0 = *(const f32x4*)src;
        f32x4 a1 = *(const f32x4*)(src + 4);
        u32x4 pk = (u32x4){cvtpk(a0[0], a0[1]), cvtpk(a0[2], a0[3]),
                           cvtpk(a1[0], a1[1]), cvtpk(a1[2], a1[3])};
        *(u32x4*)&As[row * 40 + sko] = pk;
      }
    } else {
#pragma unroll
      for (int j = 0; j < 2; ++j) {
        const int rbase = wid * 32 + j * 16;
        gload_lds16(&Xh[(size_t)(m0 + rbase + glr) * D_DIM + k0 + glc],
                    &As[rbase * 32]);
      }
    }
    if (BPRE) {
#pragma unroll
      for (int j = 0; j < 2; ++j) {
        const int rbase = wid * 32 + j * 16;
        gload_lds16(&WT[(size_t)(n0 + rbase + glr) * D_DIM + k0 + glc],
                    &Bs[rbase * 32]);
      }
    } else {
#pragma unroll
      for (int i = 0; i < 2; ++i) {
        const int s = tid + (i << 8);
        const int kr = s >> 4;
        const int mN = s & 15;
        const int nc = mN << 3;
        const float* src = &Wf[(size_t)(k0 + kr) * D_DIM + n0 + nc];
        f32x4 w0 = *(const f32x4*)src;
        f32x4 w1 = *(const f32x4*)(src + 4);
        const int cb = (((kr >> 3) ^ (mN & 3)) << 3) + (kr & 7);
#pragma unroll
        for (int j = 0; j < 4; ++j) {
          Bs[(nc + j) * 40 + cb] = f2bf(w0[j]);
          Bs[(nc + 4 + j) * 40 + cb] = f2bf(w1[j]);
        }
      }
    }
    __syncthreads();  // drains vmcnt (gload_lds) + lgkm (ds_write)
    u32x4 af[4], bfr[4];
#pragma unroll
    for (int mi = 0; mi < 4; ++mi) {
      const int row = wr * 64 + mi * 16 + lr;
      if (AF32)
        af[mi] = *(const u32x4*)&As[row * 40 + lg * 8];
      else
        af[mi] = *(const u32x4*)&As[row * 32 + ((lg ^ (row & 3)) << 3)];
    }
#pragma unroll
    for (int ni = 0; ni < 4; ++ni) {
      const int row = wc * 64 + ni * 16 + lr;
      if (BPRE)
        bfr[ni] = *(const u32x4*)&Bs[row * 32 + ((lg ^ (row & 3)) << 3)];
      else
        bfr[ni] = *(const u32x4*)&Bs[row * 40 + ((lg ^ ((row >> 3) & 3)) << 3)];
    }
#pragma unroll
    for (int mi = 0; mi < 4; ++mi)
#pragma unroll
      for (int ni = 0; ni < 4; ++ni)
        acc[mi][ni] = mfma16(af[mi], bfr[ni], acc[mi][ni]);
  }

  // epilogue (C/D: col = lane&15, row = lg*4 + reg)
#pragma unroll
  for (int ni = 0; ni < 4; ++ni) {
    const int n = n0 + wc * 64 + ni * 16 + lr;
    const float bv = bias[n];
#pragma unroll
    for (int mi = 0; mi < 4; ++mi) {
      const int mb = m0 + wr * 64 + mi * 16 + lg * 4;
      float o[4];
#pragma unroll
      for (int r = 0; r < 4; ++r) o[r] = (acc[mi][ni][r] + bv) * osc;
      if (epi == 0) {
#pragma unroll
        for (int r = 0; r < 4; ++r)
          ((float*)dstv)[(size_t)(mb + r) * D_DIM + n] = o[r];
      } else {
        const unsigned int w0 = cvtpk(o[0], o[1]);
        const unsigned int w1 = cvtpk(o[2], o[3]);
        const int bb = mb >> 11, ss = mb & (S_LEN - 1);
        const int hh = n >> 6, dd = n & (DK - 1);
        if (epi == 2) {
          union { unsigned int u[2]; unsigned long long q; } pk;
          pk.u[0] = w0; pk.u[1] = w1;
          *(unsigned long long*)&((u16*)dstv)[((size_t)((bb * N_HEADS + hh) * DK + dd)) * S_LEN + ss] = pk.q;
        } else {
          u16* dp = &((u16*)dstv)[(((size_t)(bb * N_HEADS + hh) * S_LEN) + ss) * DK + dd];
          dp[0] = (u16)w0;
          dp[DK] = (u16)(w0 >> 16);
          dp[2 * DK] = (u16)w1;
          dp[3 * DK] = (u16)(w1 >> 16);
        }
      }
    }
  }
}

template <int AF32, int BPRE>
__global__ __launch_bounds__(256) void gemm_xw(const void* __restrict__ Av,
                                               const void* __restrict__ Bv,
                                               const float* __restrict__ bias,
                                               void* __restrict__ dstv,
                                               const int epi, const float osc) {
  gemm_body<AF32, BPRE>(Av, Bv, bias, dstv, epi, osc,
                        (int)blockIdx.x * 128, (int)blockIdx.y * 128);
}

// merged Q/K/V projection: z selects input/weight/bias/dst (tail overlap)
__global__ __launch_bounds__(256) void gemm_qkv(
    const float* __restrict__ q, const float* __restrict__ k,
    const float* __restrict__ v, const u16* __restrict__ WqT,
    const u16* __restrict__ WkT, const u16* __restrict__ WvT,
    const float* __restrict__ bq, const float* __restrict__ bk,
    const float* __restrict__ bv, u16* __restrict__ Qb, u16* __restrict__ Kb,
    u16* __restrict__ VTb, const float scl) {
  const int z = blockIdx.z;
  const float* A = (z == 0) ? q : (z == 1) ? k : v;
  const u16* WT = (z == 0) ? WqT : (z == 1) ? WkT : WvT;
  const float* bias = (z == 0) ? bq : (z == 1) ? bk : bv;
  u16* dst = (z == 0) ? Qb : (z == 1) ? Kb : VTb;
  gemm_body<1, 1>(A, WT, bias, dst, (z == 2) ? 2 : 1, (z == 0) ? scl : 1.0f,
                  (int)blockIdx.x * 128, (int)blockIdx.y * 128);
}

// ---- causal flash attention (round-13 verbatim: 98.5us, conflicts=0) -------
__global__ __launch_bounds__(256) void attn_kernel(const u16* __restrict__ Qb,
                                                   const u16* __restrict__ Kb,
                                                   const u16* __restrict__ VTb,
                                                   u16* __restrict__ Xb) {
  __shared__ __align__(16) u16 Vt[2][64 * 64];   // [buf][dk][kp], chunk-swizzled
  __shared__ __align__(16) u16 Pl[4][32 * 76];   // per-wave [q_local][kpos]

  const int tid = threadIdx.x;
  const int lane = tid & 63;
  const int w = tid >> 6;
  const int lr = lane & 15;
  const int lg = lane >> 4;

  // balanced XCD-pinned decode: every CU gets qi summing to 30 (68 tiles)
  const int id = (int)blockIdx.x;
  const int xcd = id & 7;
  const int slot = id >> 3;            // 0..127
  const int bh_hi = slot & 7;
  const int qpos = slot >> 3;          // 0..15
  const int grp = qpos >> 2, pos = qpos & 3;
  const int qi = (grp == 0) ? pos : (grp == 1) ? (15 - pos)
               : (grp == 2) ? (4 + pos) : (11 - pos);
  const int q0 = qi * 128;
  const int bh = (bh_hi << 3) | xcd;
  const int h = bh & (N_HEADS - 1);
  const int b = bh >> 4;

  const u16* Qh = Qb + ((size_t)bh) * S_LEN * DK;
  const u16* Kh = Kb + ((size_t)bh) * S_LEN * DK;
  const u16* VTh = VTb + ((size_t)bh) * DK * S_LEN;

  const int wrow = q0 + w * 32;
  const int nt = (q0 >> 6) + 2;

  const int vdk = tid >> 3;        // V staging rows vdk, vdk+32
  const int vc = tid & 7;          // 16B chunk

  const u32x4 ONES = {0x3F803F80u, 0x3F803F80u, 0x3F803F80u, 0x3F803F80u};

  u32x4 qf[2][2];
#pragma unroll
  for (int m = 0; m < 2; ++m)
#pragma unroll
    for (int g = 0; g < 2; ++g)
      qf[m][g] = *(const u32x4*)&Qh[(size_t)(wrow + m * 16 + lr) * DK + g * 32 + lg * 8];

  f32x4 xacc[2][4], sacc[2];
#pragma unroll
  for (int m = 0; m < 2; ++m) {
#pragma unroll
    for (int i = 0; i < 4; ++i) xacc[m][i] = (f32x4){0.f, 0.f, 0.f, 0.f};
    sacc[m] = (f32x4){0.f, 0.f, 0.f, 0.f};
  }

  // prologue: load + stage V(0) into buf0; prefetch K(0)
  u32x4 vpre[2], kreg[8];
#pragma unroll
  for (int i = 0; i < 2; ++i)
    vpre[i] = *(const u32x4*)&VTh[(size_t)(vdk + i * 32) * S_LEN + vc * 8];
#pragma unroll
  for (int g = 0; g < 2; ++g)
#pragma unroll
    for (int tt = 0; tt < 4; ++tt)
      kreg[g * 4 + tt] = *(const u32x4*)&Kh[(size_t)(tt * 16 + lr) * DK + g * 32 + lg * 8];
#pragma unroll
  for (int i = 0; i < 2; ++i) {
    const int dk = vdk + i * 32;
    *(u32x4*)&Vt[0][dk * 64 + ((vc ^ (dk & 7)) << 3)] = vpre[i];
  }

  for (int t = 0; t < nt; ++t) {
    const int kp0 = t << 6;
    const bool wact = (kp0 <= wrow + 31);
    const bool dmask = (kp0 + 63 > wrow);
    f32x4 sc[2][4];
#pragma unroll
    for (int m = 0; m < 2; ++m)
#pragma unroll
      for (int tt = 0; tt < 4; ++tt) sc[m][tt] = (f32x4){0.f, 0.f, 0.f, 0.f};
    if (wact) {
      __builtin_amdgcn_s_setprio(1);
#pragma unroll
      for (int g = 0; g < 2; ++g)
#pragma unroll
        for (int tt = 0; tt < 4; ++tt) {
          sc[0][tt] = mfma16(kreg[g * 4 + tt], qf[0][g], sc[0][tt]);  // swapped
          sc[1][tt] = mfma16(kreg[g * 4 + tt], qf[1][g], sc[1][tt]);
        }
      __builtin_amdgcn_s_setprio(0);
      // softmax: p = exp2(s); mask only on diagonal tile; cvtpk + b64 writes
#pragma unroll
      for (int m = 0; m < 2; ++m) {
        const int qre = wrow + m * 16 + lr;
        float pv[4][4];
        if (dmask) {
#pragma unroll
          for (int tt = 0; tt < 4; ++tt)
#pragma unroll
            for (int r = 0; r < 4; ++r) {
              const int kpe = kp0 + tt * 16 + lg * 4 + r;
              float s = sc[m][tt][r];
              if (kpe > qre) s = -1e30f;
              pv[tt][r] = exp2f(s);
            }
        } else {
#pragma unroll
          for (int tt = 0; tt < 4; ++tt)
#pragma unroll
            for (int r = 0; r < 4; ++r) pv[tt][r] = exp2f(sc[m][tt][r]);
        }
#pragma unroll
        for (int tt = 0; tt < 4; ++tt) {
          uint2 pw;
          pw.x = cvtpk(pv[tt][0], pv[tt][1]);
          pw.y = cvtpk(pv[tt][2], pv[tt][3]);
          *(uint2*)&Pl[w][(m * 16 + lr) * 76 + tt * 16 + lg * 4] = pw;
        }
      }
    }
    __syncthreads();  // drains Pl + prior-tile staging; no fresh loads pending
    // prefetch K(t+1), V(t+1) AFTER the barrier
    const bool pre = (t + 1 < nt);
    if (pre) {
      const int kn = (t + 1) << 6;
#pragma unroll
      for (int i = 0; i < 2; ++i)
        vpre[i] = *(const u32x4*)&VTh[(size_t)(vdk + i * 32) * S_LEN + kn + vc * 8];
#pragma unroll
      for (int g = 0; g < 2; ++g)
#pragma unroll
        for (int tt = 0; tt < 4; ++tt)
          kreg[g * 4 + tt] = *(const u32x4*)&Kh[(size_t)(kn + tt * 16 + lr) * DK + g * 32 + lg * 8];
    }
    if (wact) {
      u32x4 pf[2][2];
#pragma unroll
      for (int m = 0; m < 2; ++m) {
        pf[m][0] = *(const u32x4*)&Pl[w][(m * 16 + lr) * 76 + lg * 8];
        pf[m][1] = *(const u32x4*)&Pl[w][(m * 16 + lr) * 76 + 32 + lg * 8];
      }
      __builtin_amdgcn_s_setprio(1);
#pragma unroll
      for (int db = 0; db < 4; ++db) {
        const int vr = db * 16 + lr;
        u32x4 vf0 = *(const u32x4*)&Vt[t & 1][vr * 64 + ((lg ^ (vr & 7)) << 3)];
        u32x4 vf1 = *(const u32x4*)&Vt[t & 1][vr * 64 + (((lg ^ 4) ^ (vr & 7)) << 3)];
#pragma unroll
        for (int m = 0; m < 2; ++m) {
          xacc[m][db] = mfma16(pf[m][0], vf0, xacc[m][db]);
          xacc[m][db] = mfma16(pf[m][1], vf1, xacc[m][db]);
        }
      }
      // row-sums on the MFMA pipe
#pragma unroll
      for (int m = 0; m < 2; ++m) {
        sacc[m] = mfma16(pf[m][0], ONES, sacc[m]);
        sacc[m] = mfma16(pf[m][1], ONES, sacc[m]);
      }
      __builtin_amdgcn_s_setprio(0);
    }
    if (pre) {
#pragma unroll
      for (int i = 0; i < 2; ++i) {
        const int dk = vdk + i * 32;
        *(u32x4*)&Vt[(t + 1) & 1][dk * 64 + ((vc ^ (dk & 7)) << 3)] = vpre[i];
      }
    }
  }

#pragma unroll
  for (int m = 0; m < 2; ++m)
#pragma unroll
    for (int r = 0; r < 4; ++r) {
      const float inv = 1.0f / fmaxf(sacc[m][r], 1e-30f);
      const int srow = wrow + m * 16 + lg * 4 + r;
      const size_t base = ((size_t)b * S_LEN + srow) * D_DIM + h * DK;
      const unsigned int w0 = cvtpk(xacc[m][0][r] * inv, xacc[m][1][r] * inv);
      const unsigned int w1 = cvtpk(xacc[m][2][r] * inv, xacc[m][3][r] * inv);
      Xb[base + 0 * 16 + lr] = (u16)w0;
      Xb[base + 1 * 16 + lr] = (u16)(w0 >> 16);
      Xb[base + 2 * 16 + lr] = (u16)w1;
      Xb[base + 3 * 16 + lr] = (u16)(w1 >> 16);
    }
}

// ---- launcher ---------------------------------------------------------------
// d_out holds Qb+Kb (bf16, 33.55MB = out_size*4B). ws: VTb + Xb (+4x WT bf16).
extern "C" void kernel_launch(void* const* d_in, const int* in_sizes, int n_in,
                              void* d_out, int out_size, void* d_ws, size_t ws_size,
                              hipStream_t stream) {
  const float* q = (const float*)d_in[0];
  const float* k = (const float*)d_in[1];
  const float* v = (const float*)d_in[2];
  const float* Wq = (const float*)d_in[4];  const float* bq = (const float*)d_in[5];
  const float* Wk = (const float*)d_in[6];  const float* bk = (const float*)d_in[7];
  const float* Wv = (const float*)d_in[8];  const float* bv = (const float*)d_in[9];
  const float* Wo = (const float*)d_in[10]; const float* bo = (const float*)d_in[11];

  u16* Qb = (u16*)d_out;
  u16* Kb = Qb + (8u << 20);
  u16* VTb = (u16*)d_ws;
  u16* Xb = VTb + (8u << 20);

  const float scl = 0.125f * 1.4426950408889634f;  // 1/sqrt(DK) * log2(e)
  const dim3 tb(256);
  const size_t need = ((size_t)(8u << 20)) * 2 * 2 + 4 * ((size_t)(1u << 20)) * 2;

  if (ws_size >= need) {
    u16* WqT = Xb + (8u << 20);
    u16* WkT = WqT + (1u << 20);
    u16* WvT = WkT + (1u << 20);
    u16* WoT = WvT + (1u << 20);
    transpose_all<<<dim3(32, 32, 4), tb, 0, stream>>>(Wq, Wk, Wv, Wo, WqT, WkT, WvT, WoT);
    gemm_qkv<<<dim3(64, 8, 3), tb, 0, stream>>>(q, k, v, WqT, WkT, WvT,
                                                bq, bk, bv, Qb, Kb, VTb, scl);
    attn_kernel<<<dim3(1024), tb, 0, stream>>>(Qb, Kb, VTb, Xb);
    gemm_xw<0, 1><<<dim3(64, 8), tb, 0, stream>>>(Xb, WoT, bo, d_out, 0, 1.0f);
  } else {
    gemm_xw<1, 0><<<dim3(64, 8), tb, 0, stream>>>(q, Wq, bq, Qb, 1, scl);
    gemm_xw<1, 0><<<dim3(64, 8), tb, 0, stream>>>(k, Wk, bk, Kb, 1, 1.0f);
    gemm_xw<1, 0><<<dim3(64, 8), tb, 0, stream>>>(v, Wv, bv, VTb, 2, 1.0f);
    attn_kernel<<<dim3(1024), tb, 0, stream>>>(Qb, Kb, VTb, Xb);
    gemm_xw<0, 0><<<dim3(64, 8), tb, 0, stream>>>(Xb, Wo, bo, d_out, 0, 1.0f);
  }
}

// Round 22
// 197.974 us; speedup vs baseline: 1.1936x; 1.0458x over previous
//
#include <hip/hip_runtime.h>

typedef unsigned short u16;
typedef __attribute__((ext_vector_type(4))) float f32x4;
typedef __attribute__((ext_vector_type(8))) __bf16 bf16x8;
typedef __attribute__((ext_vector_type(4))) unsigned int u32x4;

#define S_LEN 2048
#define D_DIM 1024
#define N_HEADS 16
#define DK 64
#define B_SZ 4

__device__ __forceinline__ u16 f2bf(float f) {
  unsigned int u = __float_as_uint(f);
  unsigned int r = (u + 0x7FFFu + ((u >> 16) & 1u)) >> 16;
  return (u16)r;
}
__device__ __forceinline__ unsigned int cvtpk(float a, float b) {
  unsigned int r;
  asm("v_cvt_pk_bf16_f32 %0, %1, %2" : "=v"(r) : "v"(a), "v"(b));
  return r;  // low16 = bf16(a), high16 = bf16(b)
}
__device__ __forceinline__ f32x4 mfma16(u32x4 a, u32x4 b, f32x4 c) {
  return __builtin_amdgcn_mfma_f32_16x16x32_bf16(
      __builtin_bit_cast(bf16x8, a), __builtin_bit_cast(bf16x8, b), c, 0, 0, 0);
}
// async global->LDS, 16B/lane; LDS dest = wave-uniform base + lane*16
__device__ __forceinline__ void gload_lds16(const void* g, void* l) {
  __builtin_amdgcn_global_load_lds(
      (const __attribute__((address_space(1))) void*)g,
      (__attribute__((address_space(3))) void*)l, 16, 0, 0);
}

// ---- fused weight transposes: WT[n][k] (bf16) = W[k][n] (f32) --------------
__global__ __launch_bounds__(256) void transpose_all(
    const float* __restrict__ W0, const float* __restrict__ W1,
    const float* __restrict__ W2, const float* __restrict__ W3,
    u16* __restrict__ T0, u16* __restrict__ T1,
    u16* __restrict__ T2, u16* __restrict__ T3) {
  __shared__ float tb[32][33];
  const int z = blockIdx.z;
  const float* W = (z == 0) ? W0 : (z == 1) ? W1 : (z == 2) ? W2 : W3;
  u16* WT = (z == 0) ? T0 : (z == 1) ? T1 : (z == 2) ? T2 : T3;
  const int tx = threadIdx.x & 31;
  const int ty0 = (threadIdx.x >> 5) << 2;
  const int bn = blockIdx.x << 5;
  const int bk = blockIdx.y << 5;
#pragma unroll
  for (int i = 0; i < 4; ++i)
    tb[ty0 + i][tx] = W[(size_t)(bk + ty0 + i) * D_DIM + bn + tx];
  __syncthreads();
#pragma unroll
  for (int i = 0; i < 4; ++i)
    WT[(size_t)(bn + ty0 + i) * D_DIM + bk + tx] = f2bf(tb[tx][ty0 + i]);
}

// ---- GEMM body (round-21 baseline + A-register prefetch on AF32 path) -----
// A f32 loads for K-step k+1 now issue AFTER barrier-2 (staging complete),
// hidden under the 32-MFMA compute phase — same post-barrier-prefetch pattern
// that paid in the attention kernel (r12). Registers are private (no WAR);
// barrier-1's vmcnt drain becomes cheap (loads landed during compute).
template <int AF32, int BPRE>
__device__ __forceinline__ void gemm_body(const void* __restrict__ Av,
                                          const void* __restrict__ Bv,
                                          const float* __restrict__ bias,
                                          void* __restrict__ dstv,
                                          const int epi, const float osc,
                                          const int m0, const int n0) {
  __shared__ __align__(16) u16 As[128 * 40];
  __shared__ __align__(16) u16 Bs[128 * 40];
  const int tid = threadIdx.x;
  const int lane = tid & 63;
  const int wid = tid >> 6;
  const int wr = wid >> 1, wc = wid & 1;
  const int lr = lane & 15, lg = lane >> 4;

  const float* Xf = (const float*)Av;
  const u16* Xh = (const u16*)Av;
  const float* Wf = (const float*)Bv;
  const u16* WT = (const u16*)Bv;

  f32x4 acc[4][4];
#pragma unroll
  for (int i = 0; i < 4; ++i)
#pragma unroll
    for (int j = 0; j < 4; ++j) acc[i][j] = (f32x4){0.f, 0.f, 0.f, 0.f};

  const int srow = tid >> 2;
  const int sko = (tid & 3) << 3;
  const int glr = lane >> 2;                       // 0..15
  const int glc = ((lane & 3) ^ (glr & 3)) << 3;   // pre-swizzled chunk (elems)

  // AF32 prologue: prefetch A registers for k0 = 0
  f32x4 apre[2][2];
  if (AF32) {
#pragma unroll
    for (int i = 0; i < 2; ++i) {
      const float* src = &Xf[(size_t)(m0 + srow + i * 64) * D_DIM + sko];
      apre[i][0] = *(const f32x4*)src;
      apre[i][1] = *(const f32x4*)(src + 4);
    }
  }

  for (int k0 = 0; k0 < D_DIM; k0 += 32) {
    __syncthreads();  // barrier-1: prev compute done with As/Bs
    if (AF32) {
#pragma unroll
      for (int i = 0; i < 2; ++i) {
        const int row = srow + i * 64;
        u32x4 pk = (u32x4){cvtpk(apre[i][0][0], apre[i][0][1]),
                           cvtpk(apre[i][0][2], apre[i][0][3]),
                           cvtpk(apre[i][1][0], apre[i][1][1]),
                           cvtpk(apre[i][1][2], apre[i][1][3])};
        *(u32x4*)&As[row * 40 + sko] = pk;
      }
    } else {
#pragma unroll
      for (int j = 0; j < 2; ++j) {
        const int rbase = wid * 32 + j * 16;
        gload_lds16(&Xh[(size_t)(m0 + rbase + glr) * D_DIM + k0 + glc],
                    &As[rbase * 32]);
      }
    }
    if (BPRE) {
#pragma unroll
      for (int j = 0; j < 2; ++j) {
        const int rbase = wid * 32 + j * 16;
        gload_lds16(&WT[(size_t)(n0 + rbase + glr) * D_DIM + k0 + glc],
                    &Bs[rbase * 32]);
      }
    } else {
#pragma unroll
      for (int i = 0; i < 2; ++i) {
        const int s = tid + (i << 8);
        const int kr = s >> 4;
        const int mN = s & 15;
        const int nc = mN << 3;
        const float* src = &Wf[(size_t)(k0 + kr) * D_DIM + n0 + nc];
        f32x4 w0 = *(const f32x4*)src;
        f32x4 w1 = *(const f32x4*)(src + 4);
        const int cb = (((kr >> 3) ^ (mN & 3)) << 3) + (kr & 7);
#pragma unroll
        for (int j = 0; j < 4; ++j) {
          Bs[(nc + j) * 40 + cb] = f2bf(w0[j]);
          Bs[(nc + 4 + j) * 40 + cb] = f2bf(w1[j]);
        }
      }
    }
    __syncthreads();  // barrier-2: staging complete (vmcnt/lgkm drained)
    // post-barrier prefetch of A(k0+32): latency hides under the MFMA phase
    if (AF32 && k0 + 32 < D_DIM) {
#pragma unroll
      for (int i = 0; i < 2; ++i) {
        const float* src = &Xf[(size_t)(m0 + srow + i * 64) * D_DIM + k0 + 32 + sko];
        apre[i][0] = *(const f32x4*)src;
        apre[i][1] = *(const f32x4*)(src + 4);
      }
    }
    u32x4 af[4], bfr[4];
#pragma unroll
    for (int mi = 0; mi < 4; ++mi) {
      const int row = wr * 64 + mi * 16 + lr;
      if (AF32)
        af[mi] = *(const u32x4*)&As[row * 40 + lg * 8];
      else
        af[mi] = *(const u32x4*)&As[row * 32 + ((lg ^ (row & 3)) << 3)];
    }
#pragma unroll
    for (int ni = 0; ni < 4; ++ni) {
      const int row = wc * 64 + ni * 16 + lr;
      if (BPRE)
        bfr[ni] = *(const u32x4*)&Bs[row * 32 + ((lg ^ (row & 3)) << 3)];
      else
        bfr[ni] = *(const u32x4*)&Bs[row * 40 + ((lg ^ ((row >> 3) & 3)) << 3)];
    }
#pragma unroll
    for (int mi = 0; mi < 4; ++mi)
#pragma unroll
      for (int ni = 0; ni < 4; ++ni)
        acc[mi][ni] = mfma16(af[mi], bfr[ni], acc[mi][ni]);
  }

  // epilogue (C/D: col = lane&15, row = lg*4 + reg)
#pragma unroll
  for (int ni = 0; ni < 4; ++ni) {
    const int n = n0 + wc * 64 + ni * 16 + lr;
    const float bv = bias[n];
#pragma unroll
    for (int mi = 0; mi < 4; ++mi) {
      const int mb = m0 + wr * 64 + mi * 16 + lg * 4;
      float o[4];
#pragma unroll
      for (int r = 0; r < 4; ++r) o[r] = (acc[mi][ni][r] + bv) * osc;
      if (epi == 0) {
#pragma unroll
        for (int r = 0; r < 4; ++r)
          ((float*)dstv)[(size_t)(mb + r) * D_DIM + n] = o[r];
      } else {
        const unsigned int w0 = cvtpk(o[0], o[1]);
        const unsigned int w1 = cvtpk(o[2], o[3]);
        const int bb = mb >> 11, ss = mb & (S_LEN - 1);
        const int hh = n >> 6, dd = n & (DK - 1);
        if (epi == 2) {
          union { unsigned int u[2]; unsigned long long q; } pk;
          pk.u[0] = w0; pk.u[1] = w1;
          *(unsigned long long*)&((u16*)dstv)[((size_t)((bb * N_HEADS + hh) * DK + dd)) * S_LEN + ss] = pk.q;
        } else {
          u16* dp = &((u16*)dstv)[(((size_t)(bb * N_HEADS + hh) * S_LEN) + ss) * DK + dd];
          dp[0] = (u16)w0;
          dp[DK] = (u16)(w0 >> 16);
          dp[2 * DK] = (u16)w1;
          dp[3 * DK] = (u16)(w1 >> 16);
        }
      }
    }
  }
}

template <int AF32, int BPRE>
__global__ __launch_bounds__(256) void gemm_xw(const void* __restrict__ Av,
                                               const void* __restrict__ Bv,
                                               const float* __restrict__ bias,
                                               void* __restrict__ dstv,
                                               const int epi, const float osc) {
  gemm_body<AF32, BPRE>(Av, Bv, bias, dstv, epi, osc,
                        (int)blockIdx.x * 128, (int)blockIdx.y * 128);
}

// merged Q/K/V projection: z selects input/weight/bias/dst (tail overlap)
__global__ __launch_bounds__(256) void gemm_qkv(
    const float* __restrict__ q, const float* __restrict__ k,
    const float* __restrict__ v, const u16* __restrict__ WqT,
    const u16* __restrict__ WkT, const u16* __restrict__ WvT,
    const float* __restrict__ bq, const float* __restrict__ bk,
    const float* __restrict__ bv, u16* __restrict__ Qb, u16* __restrict__ Kb,
    u16* __restrict__ VTb, const float scl) {
  const int z = blockIdx.z;
  const float* A = (z == 0) ? q : (z == 1) ? k : v;
  const u16* WT = (z == 0) ? WqT : (z == 1) ? WkT : WvT;
  const float* bias = (z == 0) ? bq : (z == 1) ? bk : bv;
  u16* dst = (z == 0) ? Qb : (z == 1) ? Kb : VTb;
  gemm_body<1, 1>(A, WT, bias, dst, (z == 2) ? 2 : 1, (z == 0) ? scl : 1.0f,
                  (int)blockIdx.x * 128, (int)blockIdx.y * 128);
}

// ---- causal flash attention (round-13 verbatim: 98.5us, conflicts=0) -------
__global__ __launch_bounds__(256) void attn_kernel(const u16* __restrict__ Qb,
                                                   const u16* __restrict__ Kb,
                                                   const u16* __restrict__ VTb,
                                                   u16* __restrict__ Xb) {
  __shared__ __align__(16) u16 Vt[2][64 * 64];   // [buf][dk][kp], chunk-swizzled
  __shared__ __align__(16) u16 Pl[4][32 * 76];   // per-wave [q_local][kpos]

  const int tid = threadIdx.x;
  const int lane = tid & 63;
  const int w = tid >> 6;
  const int lr = lane & 15;
  const int lg = lane >> 4;

  // balanced XCD-pinned decode: every CU gets qi summing to 30 (68 tiles)
  const int id = (int)blockIdx.x;
  const int xcd = id & 7;
  const int slot = id >> 3;            // 0..127
  const int bh_hi = slot & 7;
  const int qpos = slot >> 3;          // 0..15
  const int grp = qpos >> 2, pos = qpos & 3;
  const int qi = (grp == 0) ? pos : (grp == 1) ? (15 - pos)
               : (grp == 2) ? (4 + pos) : (11 - pos);
  const int q0 = qi * 128;
  const int bh = (bh_hi << 3) | xcd;
  const int h = bh & (N_HEADS - 1);
  const int b = bh >> 4;

  const u16* Qh = Qb + ((size_t)bh) * S_LEN * DK;
  const u16* Kh = Kb + ((size_t)bh) * S_LEN * DK;
  const u16* VTh = VTb + ((size_t)bh) * DK * S_LEN;

  const int wrow = q0 + w * 32;
  const int nt = (q0 >> 6) + 2;

  const int vdk = tid >> 3;        // V staging rows vdk, vdk+32
  const int vc = tid & 7;          // 16B chunk

  const u32x4 ONES = {0x3F803F80u, 0x3F803F80u, 0x3F803F80u, 0x3F803F80u};

  u32x4 qf[2][2];
#pragma unroll
  for (int m = 0; m < 2; ++m)
#pragma unroll
    for (int g = 0; g < 2; ++g)
      qf[m][g] = *(const u32x4*)&Qh[(size_t)(wrow + m * 16 + lr) * DK + g * 32 + lg * 8];

  f32x4 xacc[2][4], sacc[2];
#pragma unroll
  for (int m = 0; m < 2; ++m) {
#pragma unroll
    for (int i = 0; i < 4; ++i) xacc[m][i] = (f32x4){0.f, 0.f, 0.f, 0.f};
    sacc[m] = (f32x4){0.f, 0.f, 0.f, 0.f};
  }

  // prologue: load + stage V(0) into buf0; prefetch K(0)
  u32x4 vpre[2], kreg[8];
#pragma unroll
  for (int i = 0; i < 2; ++i)
    vpre[i] = *(const u32x4*)&VTh[(size_t)(vdk + i * 32) * S_LEN + vc * 8];
#pragma unroll
  for (int g = 0; g < 2; ++g)
#pragma unroll
    for (int tt = 0; tt < 4; ++tt)
      kreg[g * 4 + tt] = *(const u32x4*)&Kh[(size_t)(tt * 16 + lr) * DK + g * 32 + lg * 8];
#pragma unroll
  for (int i = 0; i < 2; ++i) {
    const int dk = vdk + i * 32;
    *(u32x4*)&Vt[0][dk * 64 + ((vc ^ (dk & 7)) << 3)] = vpre[i];
  }

  for (int t = 0; t < nt; ++t) {
    const int kp0 = t << 6;
    const bool wact = (kp0 <= wrow + 31);
    const bool dmask = (kp0 + 63 > wrow);
    f32x4 sc[2][4];
#pragma unroll
    for (int m = 0; m < 2; ++m)
#pragma unroll
      for (int tt = 0; tt < 4; ++tt) sc[m][tt] = (f32x4){0.f, 0.f, 0.f, 0.f};
    if (wact) {
      __builtin_amdgcn_s_setprio(1);
#pragma unroll
      for (int g = 0; g < 2; ++g)
#pragma unroll
        for (int tt = 0; tt < 4; ++tt) {
          sc[0][tt] = mfma16(kreg[g * 4 + tt], qf[0][g], sc[0][tt]);  // swapped
          sc[1][tt] = mfma16(kreg[g * 4 + tt], qf[1][g], sc[1][tt]);
        }
      __builtin_amdgcn_s_setprio(0);
      // softmax: p = exp2(s); mask only on diagonal tile; cvtpk + b64 writes
#pragma unroll
      for (int m = 0; m < 2; ++m) {
        const int qre = wrow + m * 16 + lr;
        float pv[4][4];
        if (dmask) {
#pragma unroll
          for (int tt = 0; tt < 4; ++tt)
#pragma unroll
            for (int r = 0; r < 4; ++r) {
              const int kpe = kp0 + tt * 16 + lg * 4 + r;
              float s = sc[m][tt][r];
              if (kpe > qre) s = -1e30f;
              pv[tt][r] = exp2f(s);
            }
        } else {
#pragma unroll
          for (int tt = 0; tt < 4; ++tt)
#pragma unroll
            for (int r = 0; r < 4; ++r) pv[tt][r] = exp2f(sc[m][tt][r]);
        }
#pragma unroll
        for (int tt = 0; tt < 4; ++tt) {
          uint2 pw;
          pw.x = cvtpk(pv[tt][0], pv[tt][1]);
          pw.y = cvtpk(pv[tt][2], pv[tt][3]);
          *(uint2*)&Pl[w][(m * 16 + lr) * 76 + tt * 16 + lg * 4] = pw;
        }
      }
    }
    __syncthreads();  // drains Pl + prior-tile staging; no fresh loads pending
    // prefetch K(t+1), V(t+1) AFTER the barrier
    const bool pre = (t + 1 < nt);
    if (pre) {
      const int kn = (t + 1) << 6;
#pragma unroll
      for (int i = 0; i < 2; ++i)
        vpre[i] = *(const u32x4*)&VTh[(size_t)(vdk + i * 32) * S_LEN + kn + vc * 8];
#pragma unroll
      for (int g = 0; g < 2; ++g)
#pragma unroll
        for (int tt = 0; tt < 4; ++tt)
          kreg[g * 4 + tt] = *(const u32x4*)&Kh[(size_t)(kn + tt * 16 + lr) * DK + g * 32 + lg * 8];
    }
    if (wact) {
      u32x4 pf[2][2];
#pragma unroll
      for (int m = 0; m < 2; ++m) {
        pf[m][0] = *(const u32x4*)&Pl[w][(m * 16 + lr) * 76 + lg * 8];
        pf[m][1] = *(const u32x4*)&Pl[w][(m * 16 + lr) * 76 + 32 + lg * 8];
      }
      __builtin_amdgcn_s_setprio(1);
#pragma unroll
      for (int db = 0; db < 4; ++db) {
        const int vr = db * 16 + lr;
        u32x4 vf0 = *(const u32x4*)&Vt[t & 1][vr * 64 + ((lg ^ (vr & 7)) << 3)];
        u32x4 vf1 = *(const u32x4*)&Vt[t & 1][vr * 64 + (((lg ^ 4) ^ (vr & 7)) << 3)];
#pragma unroll
        for (int m = 0; m < 2; ++m) {
          xacc[m][db] = mfma16(pf[m][0], vf0, xacc[m][db]);
          xacc[m][db] = mfma16(pf[m][1], vf1, xacc[m][db]);
        }
      }
      // row-sums on the MFMA pipe
#pragma unroll
      for (int m = 0; m < 2; ++m) {
        sacc[m] = mfma16(pf[m][0], ONES, sacc[m]);
        sacc[m] = mfma16(pf[m][1], ONES, sacc[m]);
      }
      __builtin_amdgcn_s_setprio(0);
    }
    if (pre) {
#pragma unroll
      for (int i = 0; i < 2; ++i) {
        const int dk = vdk + i * 32;
        *(u32x4*)&Vt[(t + 1) & 1][dk * 64 + ((vc ^ (dk & 7)) << 3)] = vpre[i];
      }
    }
  }

#pragma unroll
  for (int m = 0; m < 2; ++m)
#pragma unroll
    for (int r = 0; r < 4; ++r) {
      const float inv = 1.0f / fmaxf(sacc[m][r], 1e-30f);
      const int srow = wrow + m * 16 + lg * 4 + r;
      const size_t base = ((size_t)b * S_LEN + srow) * D_DIM + h * DK;
      const unsigned int w0 = cvtpk(xacc[m][0][r] * inv, xacc[m][1][r] * inv);
      const unsigned int w1 = cvtpk(xacc[m][2][r] * inv, xacc[m][3][r] * inv);
      Xb[base + 0 * 16 + lr] = (u16)w0;
      Xb[base + 1 * 16 + lr] = (u16)(w0 >> 16);
      Xb[base + 2 * 16 + lr] = (u16)w1;
      Xb[base + 3 * 16 + lr] = (u16)(w1 >> 16);
    }
}

// ---- launcher ---------------------------------------------------------------
// d_out holds Qb+Kb (bf16, 33.55MB = out_size*4B). ws: VTb + Xb (+4x WT bf16).
extern "C" void kernel_launch(void* const* d_in, const int* in_sizes, int n_in,
                              void* d_out, int out_size, void* d_ws, size_t ws_size,
                              hipStream_t stream) {
  const float* q = (const float*)d_in[0];
  const float* k = (const float*)d_in[1];
  const float* v = (const float*)d_in[2];
  const float* Wq = (const float*)d_in[4];  const float* bq = (const float*)d_in[5];
  const float* Wk = (const float*)d_in[6];  const float* bk = (const float*)d_in[7];
  const float* Wv = (const float*)d_in[8];  const float* bv = (const float*)d_in[9];
  const float* Wo = (const float*)d_in[10]; const float* bo = (const float*)d_in[11];

  u16* Qb = (u16*)d_out;
  u16* Kb = Qb + (8u << 20);
  u16* VTb = (u16*)d_ws;
  u16* Xb = VTb + (8u << 20);

  const float scl = 0.125f * 1.4426950408889634f;  // 1/sqrt(DK) * log2(e)
  const dim3 tb(256);
  const size_t need = ((size_t)(8u << 20)) * 2 * 2 + 4 * ((size_t)(1u << 20)) * 2;

  if (ws_size >= need) {
    u16* WqT = Xb + (8u << 20);
    u16* WkT = WqT + (1u << 20);
    u16* WvT = WkT + (1u << 20);
    u16* WoT = WvT + (1u << 20);
    transpose_all<<<dim3(32, 32, 4), tb, 0, stream>>>(Wq, Wk, Wv, Wo, WqT, WkT, WvT, WoT);
    gemm_qkv<<<dim3(64, 8, 3), tb, 0, stream>>>(q, k, v, WqT, WkT, WvT,
                                                bq, bk, bv, Qb, Kb, VTb, scl);
    attn_kernel<<<dim3(1024), tb, 0, stream>>>(Qb, Kb, VTb, Xb);
    gemm_xw<0, 1><<<dim3(64, 8), tb, 0, stream>>>(Xb, WoT, bo, d_out, 0, 1.0f);
  } else {
    gemm_xw<1, 0><<<dim3(64, 8), tb, 0, stream>>>(q, Wq, bq, Qb, 1, scl);
    gemm_xw<1, 0><<<dim3(64, 8), tb, 0, stream>>>(k, Wk, bk, Kb, 1, 1.0f);
    gemm_xw<1, 0><<<dim3(64, 8), tb, 0, stream>>>(v, Wv, bv, VTb, 2, 1.0f);
    attn_kernel<<<dim3(1024), tb, 0, stream>>>(Qb, Kb, VTb, Xb);
    gemm_xw<0, 0><<<dim3(64, 8), tb, 0, stream>>>(Xb, Wo, bo, d_out, 0, 1.0f);
  }
}